// Round 1
// baseline (1023.399 us; speedup 1.0000x reference)
//
#include <hip/hip_runtime.h>
#include <math.h>

#define NFEAT 128
#define NHID 256

// ---------------- degree count ----------------
__global__ __launch_bounds__(256) void k_count(const int* __restrict__ col,
                                               int* __restrict__ deg, int nE) {
  int e = blockIdx.x * 256 + threadIdx.x;
  if (e < nE) atomicAdd(&deg[col[e]], 1);
}

// ---------------- single-block exclusive scan + dinv ----------------
__global__ __launch_bounds__(256) void k_scan(const int* __restrict__ deg,
                                              int* __restrict__ offs,
                                              int* __restrict__ cursor,
                                              float* __restrict__ dinv, int n) {
  __shared__ int part[256];
  int t = threadIdx.x;
  int chunk = (n + 255) / 256;
  int beg = min(t * chunk, n);
  int end = min(beg + chunk, n);
  int s = 0;
  for (int i = beg; i < end; i++) s += deg[i];
  part[t] = s;
  __syncthreads();
  for (int o = 1; o < 256; o <<= 1) {
    int v = (t >= o) ? part[t - o] : 0;
    __syncthreads();
    part[t] += v;
    __syncthreads();
  }
  int run = part[t] - s;  // exclusive base for this thread's chunk
  for (int i = beg; i < end; i++) {
    offs[i] = run;
    cursor[i] = run;
    int d = deg[i];
    dinv[i] = rsqrtf((float)(d + 1));  // +1 self loop; deg>=1 so rsqrt safe
    run += d;
  }
  if (t == 255) offs[n] = part[255];
}

// ---------------- CSR fill ----------------
__global__ __launch_bounds__(256) void k_fill(const int* __restrict__ row,
                                              const int* __restrict__ col,
                                              int* __restrict__ cursor,
                                              int* __restrict__ ebuf, int nE) {
  int e = blockIdx.x * 256 + threadIdx.x;
  if (e >= nE) return;
  int c = col[e];
  int pos = atomicAdd(&cursor[c], 1);
  ebuf[pos] = row[e];
}

// ---------------- GEMM with dinv-scaled epilogue: G = (X@W) * dinv[row] ----
// W chunk (KC x OUT = 64KB) staged in LDS; thread = 1 output col x RU rows.
template <int K, int OUT, int KC, int RU, int RPB>
__global__ __launch_bounds__(256) void gemm_scale(const float* __restrict__ X,
                                                  const float* __restrict__ W,
                                                  const float* __restrict__ dinv,
                                                  float* __restrict__ G,
                                                  int nrows) {
  __shared__ float sW[KC * OUT];
  constexpr int ROWPAR = 256 / OUT;
  constexpr int NRG = RPB / (RU * ROWPAR);
  const int col = threadIdx.x % OUT;
  const int rsub = threadIdx.x / OUT;
  const int row0 = blockIdx.x * RPB;

  float acc[NRG][RU];
#pragma unroll
  for (int a = 0; a < NRG; a++)
#pragma unroll
    for (int u = 0; u < RU; u++) acc[a][u] = 0.f;

  for (int kc = 0; kc < K; kc += KC) {
    __syncthreads();
    for (int i = threadIdx.x; i < KC * OUT / 4; i += 256)
      reinterpret_cast<float4*>(sW)[i] =
          reinterpret_cast<const float4*>(W + (size_t)kc * OUT)[i];
    __syncthreads();
#pragma unroll
    for (int rg = 0; rg < NRG; rg++) {
      const int rbase = row0 + (rg * ROWPAR + rsub) * RU;
      const float* xp = X + (size_t)rbase * K + kc;
      for (int k = 0; k < KC; k += 4) {
        float4 xv[RU];
#pragma unroll
        for (int u = 0; u < RU; u++)
          xv[u] = *reinterpret_cast<const float4*>(xp + (size_t)u * K + k);
#pragma unroll
        for (int kk = 0; kk < 4; kk++) {
          float w = sW[(k + kk) * OUT + col];
#pragma unroll
          for (int u = 0; u < RU; u++)
            acc[rg][u] = fmaf(reinterpret_cast<const float*>(&xv[u])[kk], w,
                              acc[rg][u]);
        }
      }
    }
  }
#pragma unroll
  for (int rg = 0; rg < NRG; rg++) {
    const int rbase = row0 + (rg * ROWPAR + rsub) * RU;
#pragma unroll
    for (int u = 0; u < RU; u++) {
      int r = rbase + u;
      if (r < nrows) G[(size_t)r * OUT + col] = acc[rg][u] * dinv[r];
    }
  }
}

// ---------------- gather-aggregate: OUT[i] = act(dinv[i]*(g[i]+sum_in g[src]) + b)
template <int F, bool RELU>
__global__ __launch_bounds__(256) void k_agg(const float* __restrict__ G,
                                             const int* __restrict__ offs,
                                             const int* __restrict__ ebuf,
                                             const float* __restrict__ dinv,
                                             const float* __restrict__ bias,
                                             float* __restrict__ OUT, int n) {
  constexpr int VP = F / 64;  // floats per lane (4 or 2)
  int node = blockIdx.x * 4 + (threadIdx.x >> 6);
  if (node >= n) return;
  int lane = threadIdx.x & 63;
  int beg = offs[node], end = offs[node + 1];
  float acc[VP];
  const float* gs = G + (size_t)node * F + lane * VP;
#pragma unroll
  for (int u = 0; u < VP; u++) acc[u] = gs[u];  // self loop
  for (int e = beg; e < end; e++) {
    int src = ebuf[e];
    const float* gp = G + (size_t)src * F + lane * VP;
    if (VP == 4) {
      float4 v = *reinterpret_cast<const float4*>(gp);
      acc[0] += v.x; acc[1] += v.y; acc[2] += v.z; acc[3] += v.w;
    } else {
      float2 v = *reinterpret_cast<const float2*>(gp);
      acc[0] += v.x; acc[1] += v.y;
    }
  }
  float di = dinv[node];
  float* op = OUT + (size_t)node * F + lane * VP;
#pragma unroll
  for (int u = 0; u < VP; u++) {
    float v = di * acc[u] + bias[lane * VP + u];
    if (RELU) v = fmaxf(v, 0.f);
    op[u] = v;
  }
}

// ---------------- link head: sigmoid([h[m0];h[m1]] . Wl + bl) ----------------
__global__ __launch_bounds__(256) void k_link(const float* __restrict__ H,
                                              const int* __restrict__ mask,
                                              const float* __restrict__ Wl,
                                              const float* __restrict__ bl,
                                              float* __restrict__ out, int P) {
  int p = blockIdx.x * 4 + (threadIdx.x >> 6);
  if (p >= P) return;
  int lane = threadIdx.x & 63;
  int m0 = mask[2 * p], m1 = mask[2 * p + 1];
  const float* h0 = H + (size_t)m0 * NFEAT;
  const float* h1 = H + (size_t)m1 * NFEAT;
  float s = h0[lane] * Wl[lane] + h0[64 + lane] * Wl[64 + lane] +
            h1[lane] * Wl[128 + lane] + h1[64 + lane] * Wl[192 + lane];
#pragma unroll
  for (int o = 32; o; o >>= 1) s += __shfl_down(s, o);
  if (lane == 0) out[p] = 1.0f / (1.0f + expf(-(s + bl[0])));
}

extern "C" void kernel_launch(void* const* d_in, const int* in_sizes, int n_in,
                              void* d_out, int out_size, void* d_ws,
                              size_t ws_size, hipStream_t stream) {
  const int* edge = (const int*)d_in[0];
  const float* feat = (const float*)d_in[1];
  const int* mask = (const int*)d_in[2];
  const float* W1 = (const float*)d_in[3];
  const float* b1 = (const float*)d_in[4];
  const float* W2 = (const float*)d_in[5];
  const float* b2 = (const float*)d_in[6];
  const float* Wl = (const float*)d_in[7];
  const float* bl = (const float*)d_in[8];
  float* out = (float*)d_out;

  const int E = in_sizes[0] / 2;
  const int N = in_sizes[1] / NFEAT;
  const int P = in_sizes[2] / 2;
  const int* rowp = edge;
  const int* colp = edge + E;

  auto aln = [](size_t x) { return (x + 255) & ~(size_t)255; };
  char* w = (char*)d_ws;
  int* deg = (int*)w;      w += aln((size_t)N * 4);
  int* offs = (int*)w;     w += aln((size_t)(N + 1) * 4);
  int* cursor = (int*)w;   w += aln((size_t)N * 4);
  int* ebuf = (int*)w;     w += aln((size_t)E * 4);
  float* dinv = (float*)w; w += aln((size_t)N * 4);
  float* g1 = (float*)w;   w += aln((size_t)N * NHID * 4);  // reused as h
  float* t1 = (float*)w;   w += aln((size_t)N * NHID * 4);
  float* g2 = (float*)w;   w += aln((size_t)N * NFEAT * 4);
  float* h = g1;

  hipMemsetAsync(deg, 0, (size_t)N * 4, stream);
  k_count<<<(E + 255) / 256, 256, 0, stream>>>(colp, deg, E);
  k_scan<<<1, 256, 0, stream>>>(deg, offs, cursor, dinv, N);
  k_fill<<<(E + 255) / 256, 256, 0, stream>>>(rowp, colp, cursor, ebuf, E);
  // conv1: g1 = (feat @ W1) * dinv[row]; t1 = relu(dinv*(g1 self+nbrs) + b1)
  gemm_scale<128, 256, 64, 4, 16><<<(N + 15) / 16, 256, 0, stream>>>(
      feat, W1, dinv, g1, N);
  k_agg<256, true><<<(N + 3) / 4, 256, 0, stream>>>(g1, offs, ebuf, dinv, b1,
                                                    t1, N);
  // conv2: g2 = (t1 @ W2) * dinv[row]; h = dinv*(g2 self+nbrs) + b2
  gemm_scale<256, 128, 128, 4, 16><<<(N + 15) / 16, 256, 0, stream>>>(
      t1, W2, dinv, g2, N);
  k_agg<128, false><<<(N + 3) / 4, 256, 0, stream>>>(g2, offs, ebuf, dinv, b2,
                                                     h, N);
  // head
  k_link<<<(P + 3) / 4, 256, 0, stream>>>(h, mask, Wl, bl, out, P);
}

// Round 2
// 438.668 us; speedup vs baseline: 2.3330x; 2.3330x over previous
//
#include <hip/hip_runtime.h>
#include <math.h>

#define NFEAT 128
#define NHID 256

typedef __attribute__((ext_vector_type(8))) short short8;
typedef __attribute__((ext_vector_type(4))) float f32x4;

__device__ inline unsigned short f2bf(float f) {
  unsigned u = __float_as_uint(f);
  u += 0x7fffu + ((u >> 16) & 1u);
  return (unsigned short)(u >> 16);
}
__device__ inline float bflo(unsigned u) { return __uint_as_float(u << 16); }
__device__ inline float bfhi(unsigned u) { return __uint_as_float(u & 0xffff0000u); }

// ---------------- degree count ----------------
__global__ __launch_bounds__(256) void k_count(const int* __restrict__ col,
                                               int* __restrict__ deg, int nE) {
  int e = blockIdx.x * 256 + threadIdx.x;
  if (e < nE) atomicAdd(&deg[col[e]], 1);
}

// ---------------- single-block exclusive scan + dinv ----------------
__global__ __launch_bounds__(1024) void k_scan(const int* __restrict__ deg,
                                               int* __restrict__ offs,
                                               int* __restrict__ cursor,
                                               float* __restrict__ dinv, int n) {
  __shared__ int part[1024];
  int t = threadIdx.x;
  int chunk = (n + 1023) / 1024;
  int beg = min(t * chunk, n);
  int end = min(beg + chunk, n);
  int s = 0;
  for (int i = beg; i < end; i++) s += deg[i];
  part[t] = s;
  __syncthreads();
  for (int o = 1; o < 1024; o <<= 1) {
    int v = (t >= o) ? part[t - o] : 0;
    __syncthreads();
    part[t] += v;
    __syncthreads();
  }
  int run = part[t] - s;  // exclusive base for this thread's chunk
  for (int i = beg; i < end; i++) {
    offs[i] = run;
    cursor[i] = run;
    int d = deg[i];
    dinv[i] = rsqrtf((float)(d + 1));  // +1 self loop
    run += d;
  }
  if (t == 1023) offs[n] = part[1023];
}

// ---------------- CSR fill ----------------
__global__ __launch_bounds__(256) void k_fill(const int* __restrict__ row,
                                              const int* __restrict__ col,
                                              int* __restrict__ cursor,
                                              int* __restrict__ ebuf, int nE) {
  int e = blockIdx.x * 256 + threadIdx.x;
  if (e >= nE) return;
  int c = col[e];
  int pos = atomicAdd(&cursor[c], 1);
  ebuf[pos] = row[e];
}

// ---------------- pack W (fp32 row-major [K][OUT]) into bf16 B-fragments ----
// frag(nt, ks): lane l holds B[k = ks*32 + (l>>4)*8 + j][n = nt*16 + (l&15)]
template <int K, int OUT>
__global__ __launch_bounds__(256) void k_packW(const float* __restrict__ W,
                                               unsigned short* __restrict__ Wp) {
  constexpr int KS = K / 32;
  constexpr int NT = OUT / 16;
  int idx = blockIdx.x * 256 + threadIdx.x;
  if (idx >= NT * KS * 64) return;
  int lane = idx & 63;
  int t = idx >> 6;
  int ks = t % KS;
  int nt = t / KS;
  int n = nt * 16 + (lane & 15);
  int k0 = ks * 32 + (lane >> 4) * 8;
  unsigned short v[8];
#pragma unroll
  for (int j = 0; j < 8; j++) v[j] = f2bf(W[(size_t)(k0 + j) * OUT + n]);
  *reinterpret_cast<short8*>(Wp + (size_t)idx * 8) =
      *reinterpret_cast<short8*>(v);
}

// ---------------- xs = bf16(dinv[row] * X) ----------------
__global__ __launch_bounds__(256) void k_cvt(const float* __restrict__ X,
                                             const float* __restrict__ dinv,
                                             unsigned short* __restrict__ xs,
                                             int n) {
  int i4 = blockIdx.x * 256 + threadIdx.x;  // float4 index, 32 per row
  if (i4 >= n * 32) return;
  int row = i4 >> 5;
  float4 v = reinterpret_cast<const float4*>(X)[i4];
  float d = dinv[row];
  unsigned short o[4] = {f2bf(v.x * d), f2bf(v.y * d), f2bf(v.z * d),
                         f2bf(v.w * d)};
  reinterpret_cast<ushort4*>(xs)[i4] = *reinterpret_cast<ushort4*>(o);
}

// ---------------- bf16 gather-aggregate over 128-wide rows ----------------
// OUT[i] = bf16( dinv[i]*(G[i] + sum_{src in-edges} G[src]) + bias )
__global__ __launch_bounds__(256) void k_agg_bf(
    const unsigned int* __restrict__ G, const int* __restrict__ offs,
    const int* __restrict__ ebuf, const float* __restrict__ dinv,
    const float* __restrict__ bias, unsigned int* __restrict__ OUTP, int n) {
  int node = blockIdx.x * 4 + (threadIdx.x >> 6);
  if (node >= n) return;
  int lane = threadIdx.x & 63;
  int beg = offs[node], end = offs[node + 1];
  unsigned su = G[(size_t)node * 64 + lane];
  float a0 = bflo(su), a1 = bfhi(su);
  int e = beg;
  for (; e + 4 <= end; e += 4) {
    int s0 = ebuf[e], s1 = ebuf[e + 1], s2 = ebuf[e + 2], s3 = ebuf[e + 3];
    unsigned v0 = G[(size_t)s0 * 64 + lane];
    unsigned v1 = G[(size_t)s1 * 64 + lane];
    unsigned v2 = G[(size_t)s2 * 64 + lane];
    unsigned v3 = G[(size_t)s3 * 64 + lane];
    a0 += bflo(v0) + bflo(v1) + bflo(v2) + bflo(v3);
    a1 += bfhi(v0) + bfhi(v1) + bfhi(v2) + bfhi(v3);
  }
  for (; e < end; e++) {
    unsigned v = G[(size_t)ebuf[e] * 64 + lane];
    a0 += bflo(v);
    a1 += bfhi(v);
  }
  float d = dinv[node];
  a0 *= d;
  a1 *= d;
  if (bias) {
    a0 += bias[2 * lane];
    a1 += bias[2 * lane + 1];
  }
  OUTP[(size_t)node * 64 + lane] =
      (unsigned)f2bf(a0) | ((unsigned)f2bf(a1) << 16);
}

// ---------------- MFMA GEMM: C[N,OUT] = epi(A[N,K] @ B) ----------------
// MODE 0: epi = relu(x + bias[col]), MODE 1: epi = x * dinv[row]
// wave computes 16 rows x 64 cols; A,C bf16 row-major, B pre-packed frags.
template <int K, int OUT, int MODE>
__global__ __launch_bounds__(256) void k_mfma(
    const unsigned short* __restrict__ A, const unsigned short* __restrict__ Bp,
    const float* __restrict__ bias, const float* __restrict__ dinv,
    unsigned short* __restrict__ C, int nrt) {
  constexpr int KS = K / 32;
  constexpr int CG = OUT / 64;
  int gw = (blockIdx.x * 256 + threadIdx.x) >> 6;
  int lane = threadIdx.x & 63;
  int rt = gw / CG, cg = gw % CG;
  if (rt >= nrt) return;
  int m0 = rt * 16;
  int mrow = m0 + (lane & 15);
  int quad = lane >> 4;
  f32x4 acc[4] = {};
  const short8* Ap =
      reinterpret_cast<const short8*>(A + (size_t)mrow * K + quad * 8);
#pragma unroll
  for (int ks = 0; ks < KS; ks++) {
    short8 a = Ap[ks * 4];  // advance k by 32 shorts = 4 short8
#pragma unroll
    for (int ct = 0; ct < 4; ct++) {
      int nt = cg * 4 + ct;
      short8 b = *reinterpret_cast<const short8*>(
          Bp + ((size_t)(nt * KS + ks) * 64 + lane) * 8);
      acc[ct] = __builtin_amdgcn_mfma_f32_16x16x32_bf16(a, b, acc[ct], 0, 0, 0);
    }
  }
  int r0 = m0 + quad * 4;
#pragma unroll
  for (int ct = 0; ct < 4; ct++) {
    int c = (cg * 4 + ct) * 16 + (lane & 15);
    float bv = (MODE == 0) ? bias[c] : 0.f;
#pragma unroll
    for (int i = 0; i < 4; i++) {
      float v = acc[ct][i];
      if (MODE == 0) {
        v += bv;
        v = fmaxf(v, 0.f);
      } else {
        v *= dinv[r0 + i];
      }
      C[(size_t)(r0 + i) * OUT + c] = f2bf(v);
    }
  }
}

// ---------------- link head: sigmoid([h[m0];h[m1]] . Wl + bl) ----------------
__global__ __launch_bounds__(256) void k_head(const unsigned int* __restrict__ H,
                                              const int* __restrict__ mask,
                                              const float* __restrict__ Wl,
                                              const float* __restrict__ bl,
                                              float* __restrict__ out, int P) {
  int p = blockIdx.x * 4 + (threadIdx.x >> 6);
  if (p >= P) return;
  int lane = threadIdx.x & 63;
  int m0 = mask[2 * p], m1 = mask[2 * p + 1];
  unsigned u0 = H[(size_t)m0 * 64 + lane];
  unsigned u1 = H[(size_t)m1 * 64 + lane];
  float s = bflo(u0) * Wl[2 * lane] + bfhi(u0) * Wl[2 * lane + 1] +
            bflo(u1) * Wl[128 + 2 * lane] + bfhi(u1) * Wl[129 + 2 * lane];
#pragma unroll
  for (int o = 32; o; o >>= 1) s += __shfl_down(s, o);
  if (lane == 0) out[p] = 1.0f / (1.0f + expf(-(s + bl[0])));
}

extern "C" void kernel_launch(void* const* d_in, const int* in_sizes, int n_in,
                              void* d_out, int out_size, void* d_ws,
                              size_t ws_size, hipStream_t stream) {
  const int* edge = (const int*)d_in[0];
  const float* feat = (const float*)d_in[1];
  const int* mask = (const int*)d_in[2];
  const float* W1 = (const float*)d_in[3];
  const float* b1 = (const float*)d_in[4];
  const float* W2 = (const float*)d_in[5];
  const float* b2 = (const float*)d_in[6];
  const float* Wl = (const float*)d_in[7];
  const float* bl = (const float*)d_in[8];
  float* out = (float*)d_out;

  const int E = in_sizes[0] / 2;
  const int N = in_sizes[1] / NFEAT;
  const int P = in_sizes[2] / 2;
  const int* rowp = edge;
  const int* colp = edge + E;
  const int nrt = N / 16;  // N = 50000 -> 3125 exact

  auto aln = [](size_t x) { return (x + 255) & ~(size_t)255; };
  char* w = (char*)d_ws;
  int* deg = (int*)w;              w += aln((size_t)N * 4);
  int* offs = (int*)w;             w += aln((size_t)(N + 1) * 4);
  int* cursor = (int*)w;           w += aln((size_t)N * 4);
  int* ebuf = (int*)w;             w += aln((size_t)E * 4);
  float* dinv = (float*)w;         w += aln((size_t)N * 4);
  unsigned short* xs = (unsigned short*)w;  w += aln((size_t)N * NFEAT * 2);
  unsigned short* z = (unsigned short*)w;   w += aln((size_t)N * NFEAT * 2);
  unsigned short* h1 = (unsigned short*)w;  w += aln((size_t)N * NHID * 2);
  unsigned short* g2 = (unsigned short*)w;  w += aln((size_t)N * NFEAT * 2);
  unsigned short* hf = (unsigned short*)w;  w += aln((size_t)N * NFEAT * 2);
  unsigned short* W1p = (unsigned short*)w; w += aln((size_t)NFEAT * NHID * 2);
  unsigned short* W2p = (unsigned short*)w; w += aln((size_t)NHID * NFEAT * 2);

  hipMemsetAsync(deg, 0, (size_t)N * 4, stream);
  k_count<<<(E + 255) / 256, 256, 0, stream>>>(colp, deg, E);
  k_scan<<<1, 1024, 0, stream>>>(deg, offs, cursor, dinv, N);
  k_fill<<<(E + 255) / 256, 256, 0, stream>>>(rowp, colp, cursor, ebuf, E);
  k_packW<NFEAT, NHID><<<16, 256, 0, stream>>>(W1, W1p);
  k_packW<NHID, NFEAT><<<16, 256, 0, stream>>>(W2, W2p);

  // xs = bf16(dinv * X)
  k_cvt<<<(N * 32 + 255) / 256, 256, 0, stream>>>(feat, dinv, xs, N);
  // z = dinv .* (sum_in xs + xs_self)            [= A_norm @ X, bf16]
  k_agg_bf<<<(N + 3) / 4, 256, 0, stream>>>((const unsigned*)xs, offs, ebuf,
                                            dinv, nullptr, (unsigned*)z, N);
  // h1 = relu(z @ W1 + b1)
  k_mfma<NFEAT, NHID, 0><<<(nrt * (NHID / 64) + 3) / 4, 256, 0, stream>>>(
      z, W1p, b1, nullptr, h1, nrt);
  // g2 = (h1 @ W2) .* dinv[row]
  k_mfma<NHID, NFEAT, 1><<<(nrt * (NFEAT / 64) + 3) / 4, 256, 0, stream>>>(
      h1, W2p, nullptr, dinv, g2, nrt);
  // h = dinv .* (sum_in g2 + g2_self) + b2
  k_agg_bf<<<(N + 3) / 4, 256, 0, stream>>>((const unsigned*)g2, offs, ebuf,
                                            dinv, b2, (unsigned*)hf, N);
  // head
  k_head<<<(P + 3) / 4, 256, 0, stream>>>((const unsigned*)hf, mask, Wl, bl,
                                          out, P);
}

// Round 3
// 311.897 us; speedup vs baseline: 3.2812x; 1.4065x over previous
//
#include <hip/hip_runtime.h>
#include <math.h>

#define NFEAT 128
#define NHID 256

typedef __attribute__((ext_vector_type(8))) short short8;
typedef __attribute__((ext_vector_type(4))) float f32x4;

__device__ inline unsigned short f2bf(float f) {
  unsigned u = __float_as_uint(f);
  u += 0x7fffu + ((u >> 16) & 1u);
  return (unsigned short)(u >> 16);
}
__device__ inline float bflo(unsigned u) { return __uint_as_float(u << 16); }
__device__ inline float bfhi(unsigned u) { return __uint_as_float(u & 0xffff0000u); }

// ---------------- degree count ----------------
__global__ __launch_bounds__(256) void k_count(const int* __restrict__ col,
                                               int* __restrict__ deg, int nE) {
  int e = blockIdx.x * 256 + threadIdx.x;
  if (e < nE) atomicAdd(&deg[col[e]], 1);
}

// ---------------- phase 1: per-block degree sums ----------------
__global__ __launch_bounds__(256) void k_bsum(const int* __restrict__ deg,
                                              int* __restrict__ bsum, int n) {
  int i = blockIdx.x * 256 + threadIdx.x;
  int v = (i < n) ? deg[i] : 0;
#pragma unroll
  for (int o = 32; o; o >>= 1) v += __shfl_down(v, o);
  __shared__ int ws[4];
  if ((threadIdx.x & 63) == 0) ws[threadIdx.x >> 6] = v;
  __syncthreads();
  if (threadIdx.x == 0) bsum[blockIdx.x] = ws[0] + ws[1] + ws[2] + ws[3];
}

// ---------------- phase 2: scan block sums (nb <= 256) ----------------
__global__ __launch_bounds__(256) void k_bscan(const int* __restrict__ bsum,
                                               int* __restrict__ bbase, int nb) {
  __shared__ int sh[256];
  int t = threadIdx.x;
  int v = (t < nb) ? bsum[t] : 0;
  sh[t] = v;
  __syncthreads();
  for (int o = 1; o < 256; o <<= 1) {
    int u = (t >= o) ? sh[t - o] : 0;
    __syncthreads();
    sh[t] += u;
    __syncthreads();
  }
  bbase[t] = sh[t] - v;  // exclusive base per block
}

// ---------------- phase 3: per-element offsets + dinv ----------------
__global__ __launch_bounds__(256) void k_offs(const int* __restrict__ deg,
                                              const int* __restrict__ bbase,
                                              int* __restrict__ offs,
                                              int* __restrict__ cursor,
                                              float* __restrict__ dinv, int n) {
  __shared__ int sh[256];
  int t = threadIdx.x;
  int i = blockIdx.x * 256 + t;
  int d = (i < n) ? deg[i] : 0;
  sh[t] = d;
  __syncthreads();
  for (int o = 1; o < 256; o <<= 1) {
    int u = (t >= o) ? sh[t - o] : 0;
    __syncthreads();
    sh[t] += u;
    __syncthreads();
  }
  if (i < n) {
    int off = bbase[blockIdx.x] + sh[t] - d;
    offs[i] = off;
    cursor[i] = off;
    dinv[i] = rsqrtf((float)(d + 1));  // +1 self loop
    if (i == n - 1) offs[n] = off + d;
  }
}

// ---------------- CSR fill ----------------
__global__ __launch_bounds__(256) void k_fill(const int* __restrict__ row,
                                              const int* __restrict__ col,
                                              int* __restrict__ cursor,
                                              int* __restrict__ ebuf, int nE) {
  int e = blockIdx.x * 256 + threadIdx.x;
  if (e >= nE) return;
  int c = col[e];
  int pos = atomicAdd(&cursor[c], 1);
  ebuf[pos] = row[e];
}

// ---------------- pack both W matrices into bf16 B-fragments ----------------
// frag(nt, ks): lane l holds B[k = ks*32 + (l>>4)*8 + j][n = nt*16 + (l&15)]
__device__ inline void packOne(const float* __restrict__ W,
                               unsigned short* __restrict__ Wp, int idx, int KS,
                               int OUT) {
  int lane = idx & 63;
  int t = idx >> 6;
  int ks = t % KS;
  int nt = t / KS;
  int n = nt * 16 + (lane & 15);
  int k0 = ks * 32 + (lane >> 4) * 8;
  unsigned short v[8];
#pragma unroll
  for (int j = 0; j < 8; j++) v[j] = f2bf(W[(size_t)(k0 + j) * OUT + n]);
  *reinterpret_cast<short8*>(Wp + (size_t)idx * 8) =
      *reinterpret_cast<short8*>(v);
}

__global__ __launch_bounds__(256) void k_packW_both(
    const float* __restrict__ W1, const float* __restrict__ W2,
    unsigned short* __restrict__ W1p, unsigned short* __restrict__ W2p) {
  int idx = blockIdx.x * 256 + threadIdx.x;
  // W1: K=128 (KS=4), OUT=256 (NT=16) -> 4096 items
  // W2: K=256 (KS=8), OUT=128 (NT=8)  -> 4096 items
  if (idx < 4096) packOne(W1, W1p, idx, 4, 256);
  else packOne(W2, W2p, idx - 4096, 8, 128);
}

// ---------------- xs = bf16(dinv[row] * X) ----------------
__global__ __launch_bounds__(256) void k_cvt(const float* __restrict__ X,
                                             const float* __restrict__ dinv,
                                             unsigned short* __restrict__ xs,
                                             int n) {
  int i4 = blockIdx.x * 256 + threadIdx.x;  // float4 index, 32 per row
  if (i4 >= n * 32) return;
  int row = i4 >> 5;
  float4 v = reinterpret_cast<const float4*>(X)[i4];
  float d = dinv[row];
  unsigned short o[4] = {f2bf(v.x * d), f2bf(v.y * d), f2bf(v.z * d),
                         f2bf(v.w * d)};
  reinterpret_cast<ushort4*>(xs)[i4] = *reinterpret_cast<ushort4*>(o);
}

// ---------------- bf16 gather-aggregate over 128-wide rows ----------------
// OUT[i] = bf16( dinv[i]*(G[i] + sum_{src in-edges} G[src]) + bias )
__global__ __launch_bounds__(256) void k_agg_bf(
    const unsigned int* __restrict__ G, const int* __restrict__ offs,
    const int* __restrict__ ebuf, const float* __restrict__ dinv,
    const float* __restrict__ bias, unsigned int* __restrict__ OUTP, int n) {
  int node = blockIdx.x * 4 + (threadIdx.x >> 6);
  if (node >= n) return;
  int lane = threadIdx.x & 63;
  int beg = offs[node], end = offs[node + 1];
  unsigned su = G[(size_t)node * 64 + lane];
  float a0 = bflo(su), a1 = bfhi(su);
  int e = beg;
  for (; e + 4 <= end; e += 4) {
    int s0 = ebuf[e], s1 = ebuf[e + 1], s2 = ebuf[e + 2], s3 = ebuf[e + 3];
    unsigned v0 = G[(size_t)s0 * 64 + lane];
    unsigned v1 = G[(size_t)s1 * 64 + lane];
    unsigned v2 = G[(size_t)s2 * 64 + lane];
    unsigned v3 = G[(size_t)s3 * 64 + lane];
    a0 += bflo(v0) + bflo(v1) + bflo(v2) + bflo(v3);
    a1 += bfhi(v0) + bfhi(v1) + bfhi(v2) + bfhi(v3);
  }
  for (; e < end; e++) {
    unsigned v = G[(size_t)ebuf[e] * 64 + lane];
    a0 += bflo(v);
    a1 += bfhi(v);
  }
  float d = dinv[node];
  a0 *= d;
  a1 *= d;
  if (bias) {
    a0 += bias[2 * lane];
    a1 += bias[2 * lane + 1];
  }
  OUTP[(size_t)node * 64 + lane] =
      (unsigned)f2bf(a0) | ((unsigned)f2bf(a1) << 16);
}

// ---------------- MFMA GEMM: C[N,OUT] = epi(A[N,K] @ B) ----------------
// MODE 0: epi = relu(x + bias[col]), MODE 1: epi = x * dinv[row]
template <int K, int OUT, int MODE>
__global__ __launch_bounds__(256) void k_mfma(
    const unsigned short* __restrict__ A, const unsigned short* __restrict__ Bp,
    const float* __restrict__ bias, const float* __restrict__ dinv,
    unsigned short* __restrict__ C, int nrt) {
  constexpr int KS = K / 32;
  constexpr int CG = OUT / 64;
  int gw = (blockIdx.x * 256 + threadIdx.x) >> 6;
  int lane = threadIdx.x & 63;
  int rt = gw / CG, cg = gw % CG;
  if (rt >= nrt) return;
  int m0 = rt * 16;
  int mrow = m0 + (lane & 15);
  int quad = lane >> 4;
  f32x4 acc[4] = {};
  const short8* Ap =
      reinterpret_cast<const short8*>(A + (size_t)mrow * K + quad * 8);
#pragma unroll
  for (int ks = 0; ks < KS; ks++) {
    short8 a = Ap[ks * 4];  // advance k by 32 shorts = 4 short8
#pragma unroll
    for (int ct = 0; ct < 4; ct++) {
      int nt = cg * 4 + ct;
      short8 b = *reinterpret_cast<const short8*>(
          Bp + ((size_t)(nt * KS + ks) * 64 + lane) * 8);
      acc[ct] = __builtin_amdgcn_mfma_f32_16x16x32_bf16(a, b, acc[ct], 0, 0, 0);
    }
  }
  int r0 = m0 + quad * 4;
#pragma unroll
  for (int ct = 0; ct < 4; ct++) {
    int c = (cg * 4 + ct) * 16 + (lane & 15);
    float bv = (MODE == 0) ? bias[c] : 0.f;
#pragma unroll
    for (int i = 0; i < 4; i++) {
      float v = acc[ct][i];
      if (MODE == 0) {
        v += bv;
        v = fmaxf(v, 0.f);
      } else {
        v *= dinv[r0 + i];
      }
      C[(size_t)(r0 + i) * OUT + c] = f2bf(v);
    }
  }
}

// ---------------- link head: sigmoid([h[m0];h[m1]] . Wl + bl) ----------------
__global__ __launch_bounds__(256) void k_head(const unsigned int* __restrict__ H,
                                              const int* __restrict__ mask,
                                              const float* __restrict__ Wl,
                                              const float* __restrict__ bl,
                                              float* __restrict__ out, int P) {
  int p = blockIdx.x * 4 + (threadIdx.x >> 6);
  if (p >= P) return;
  int lane = threadIdx.x & 63;
  int m0 = mask[2 * p], m1 = mask[2 * p + 1];
  unsigned u0 = H[(size_t)m0 * 64 + lane];
  unsigned u1 = H[(size_t)m1 * 64 + lane];
  float s = bflo(u0) * Wl[2 * lane] + bfhi(u0) * Wl[2 * lane + 1] +
            bflo(u1) * Wl[128 + 2 * lane] + bfhi(u1) * Wl[129 + 2 * lane];
#pragma unroll
  for (int o = 32; o; o >>= 1) s += __shfl_down(s, o);
  if (lane == 0) out[p] = 1.0f / (1.0f + expf(-(s + bl[0])));
}

extern "C" void kernel_launch(void* const* d_in, const int* in_sizes, int n_in,
                              void* d_out, int out_size, void* d_ws,
                              size_t ws_size, hipStream_t stream) {
  const int* edge = (const int*)d_in[0];
  const float* feat = (const float*)d_in[1];
  const int* mask = (const int*)d_in[2];
  const float* W1 = (const float*)d_in[3];
  const float* b1 = (const float*)d_in[4];
  const float* W2 = (const float*)d_in[5];
  const float* b2 = (const float*)d_in[6];
  const float* Wl = (const float*)d_in[7];
  const float* bl = (const float*)d_in[8];
  float* out = (float*)d_out;

  const int E = in_sizes[0] / 2;
  const int N = in_sizes[1] / NFEAT;
  const int P = in_sizes[2] / 2;
  const int* rowp = edge;
  const int* colp = edge + E;
  const int nrt = N / 16;  // N = 50000 -> 3125 exact
  const int nblk = (N + 255) / 256;  // 196 for N=50000 (<= 256 required)

  auto aln = [](size_t x) { return (x + 255) & ~(size_t)255; };
  char* w = (char*)d_ws;
  int* deg = (int*)w;              w += aln((size_t)N * 4);
  int* offs = (int*)w;             w += aln((size_t)(N + 1) * 4);
  int* cursor = (int*)w;           w += aln((size_t)N * 4);
  int* ebuf = (int*)w;             w += aln((size_t)E * 4);
  float* dinv = (float*)w;         w += aln((size_t)N * 4);
  int* bsum = (int*)w;             w += aln((size_t)256 * 4);
  int* bbase = (int*)w;            w += aln((size_t)256 * 4);
  unsigned short* xs = (unsigned short*)w;  w += aln((size_t)N * NFEAT * 2);
  unsigned short* z = (unsigned short*)w;   w += aln((size_t)N * NFEAT * 2);
  unsigned short* h1 = (unsigned short*)w;  w += aln((size_t)N * NHID * 2);
  unsigned short* g2 = (unsigned short*)w;  w += aln((size_t)N * NFEAT * 2);
  unsigned short* hf = (unsigned short*)w;  w += aln((size_t)N * NFEAT * 2);
  unsigned short* W1p = (unsigned short*)w; w += aln((size_t)NFEAT * NHID * 2);
  unsigned short* W2p = (unsigned short*)w; w += aln((size_t)NHID * NFEAT * 2);

  hipMemsetAsync(deg, 0, (size_t)N * 4, stream);
  k_count<<<(E + 255) / 256, 256, 0, stream>>>(colp, deg, E);
  k_bsum<<<nblk, 256, 0, stream>>>(deg, bsum, N);
  k_bscan<<<1, 256, 0, stream>>>(bsum, bbase, nblk);
  k_offs<<<nblk, 256, 0, stream>>>(deg, bbase, offs, cursor, dinv, N);
  k_fill<<<(E + 255) / 256, 256, 0, stream>>>(rowp, colp, cursor, ebuf, E);
  k_packW_both<<<32, 256, 0, stream>>>(W1, W2, W1p, W2p);

  // xs = bf16(dinv * X)
  k_cvt<<<(N * 32 + 255) / 256, 256, 0, stream>>>(feat, dinv, xs, N);
  // z = dinv .* (sum_in xs + xs_self)            [= A_norm @ X, bf16]
  k_agg_bf<<<(N + 3) / 4, 256, 0, stream>>>((const unsigned*)xs, offs, ebuf,
                                            dinv, nullptr, (unsigned*)z, N);
  // h1 = relu(z @ W1 + b1)
  k_mfma<NFEAT, NHID, 0><<<(nrt * (NHID / 64) + 3) / 4, 256, 0, stream>>>(
      z, W1p, b1, nullptr, h1, nrt);
  // g2 = (h1 @ W2) .* dinv[row]
  k_mfma<NHID, NFEAT, 1><<<(nrt * (NFEAT / 64) + 3) / 4, 256, 0, stream>>>(
      h1, W2p, nullptr, dinv, g2, nrt);
  // h = dinv .* (sum_in g2 + g2_self) + b2
  k_agg_bf<<<(N + 3) / 4, 256, 0, stream>>>((const unsigned*)g2, offs, ebuf,
                                            dinv, b2, (unsigned*)hf, N);
  // head
  k_head<<<(P + 3) / 4, 256, 0, stream>>>((const unsigned*)hf, mask, Wl, bl,
                                          out, P);
}